// Round 1
// 596.300 us; speedup vs baseline: 1.0721x; 1.0721x over previous
//
#include <hip/hip_runtime.h>

// Problem constants (reference.py)
#define N_ENV 100000
#define DIM   400
#define MPTS  2000
#define NSTR  2000
#define NTRN  100

// GEMM tiling
#define BM 128
#define BK 32
#define NPAD 100096              // 782 * 128
#define KPAD 416                 // 13 * 32
#define MPAD 2048                // 16 * 128
#define KTILES (KPAD / BK)       // 13
#define MSTEPS (MPAD / 256)      // 8 outer column steps (256 cols: 4 wcol waves x 64)
#define LDST 424                 // LDS row stride in shorts: 848 B = 20 banks mod 32 -> 2-way (free)

typedef __attribute__((ext_vector_type(8))) short short8;
typedef __attribute__((ext_vector_type(4))) float float4v;

__device__ __forceinline__ unsigned short f2bf(float f) {
  union { float f; unsigned int u; } v; v.f = f;
  unsigned int u = v.u;
  u += 0x7fffu + ((u >> 16) & 1u);   // round-to-nearest-even
  return (unsigned short)(u >> 16);
}
__device__ __forceinline__ float bf2f(unsigned short s) {
  union { unsigned int u; float f; } v; v.u = ((unsigned int)s) << 16;
  return v.f;
}

// ---------------------------------------------------------------------------
// prep: wm[m] = weights[col_seg[m]] (0 in pad region), zero d_out
// ---------------------------------------------------------------------------
__global__ __launch_bounds__(256) void prep_kernel(
    const float* __restrict__ w, const int* __restrict__ col_seg,
    float* __restrict__ wm, float* __restrict__ out) {
  int t = blockIdx.x * 256 + threadIdx.x;
  if (t < MPAD) wm[t] = (t < MPTS) ? w[col_seg[t]] : 0.f;
  if (t < NSTR) out[t] = 0.f;
}

// ---------------------------------------------------------------------------
// B swizzle: fp32 support_points [MPTS,DIM] -> bf16 fragments in exact
// per-lane load order: Bsw[((pn*13+kt)*8+cf)*64+lane][e] =
//   B[pn*128+cf*16+(lane&15)][kt*32+(lane>>4)*8+e]  (0 outside MPTS/DIM)
// Inner-loop bf load becomes a fully coalesced global_load_dwordx4.
// (pn = 128-col panel index, 0..15 — layout unchanged from prior round)
// ---------------------------------------------------------------------------
__global__ __launch_bounds__(256) void bswz_kernel(
    const float* __restrict__ sp, short8* __restrict__ Bsw) {
  int u = blockIdx.x * 256 + threadIdx.x;     // < 16*13*8*64 = 106496
  int lane = u & 63;
  int v = u >> 6;          // ((pn*13+kt)*8+cf)
  int cf = v & 7;
  int w = v >> 3;          // pn*13+kt
  int kt = w % 13;
  int pn = w / 13;
  int col = pn * 128 + cf * 16 + (lane & 15);
  int kb  = kt * 32 + ((lane >> 4) << 3);
  short8 o = (short8){0, 0, 0, 0, 0, 0, 0, 0};
  if (col < MPTS && kb < DIM) {   // DIM divisible by 8: chunks never straddle
    const float* p = sp + (size_t)col * DIM + kb;
    float4 a = *(const float4*)p;
    float4 b = *(const float4*)(p + 4);
    o[0] = (short)f2bf(a.x); o[1] = (short)f2bf(a.y);
    o[2] = (short)f2bf(a.z); o[3] = (short)f2bf(a.w);
    o[4] = (short)f2bf(b.x); o[5] = (short)f2bf(b.y);
    o[6] = (short)f2bf(b.z); o[7] = (short)f2bf(b.w);
  }
  Bsw[u] = o;
}

// ---------------------------------------------------------------------------
// Fused: load 128-row fp32 A-band (coalesced, once) -> normalize -> bf16 in
// padded LDS (persistent). 512 threads = 8 waves (2 wrow x 4 wcol): the
// round-3 kernel had 4 waves = 1 wave/SIMD (Occupancy 9.7%, MfmaUtil 14%),
// fully latency-exposed. 2 waves/SIMD lets one wave's MFMA burst hide the
// other's L2 B-load + LDS-read latency. Per-CU work, LDS footprint, and
// global traffic are unchanged.
// Loop 8 col-steps (256 cols) x 13 k-tiles: af from LDS, bf from swizzled
// global (L2-resident), 16x16x32 bf16 MFMA. No barriers in K-loop.
// Epilogue: vacc[row] += wm[col]*C^2 across col-steps (regs), then 16-lane
// shuffle reduce + atomicAdd into out[row_seg[n]].
// ---------------------------------------------------------------------------
__global__ __launch_bounds__(512, 1) void gemm_fused_kernel(
    const float* __restrict__ A,        // raw power_spectrum fp32 [N_ENV][DIM]
    const short8* __restrict__ Bsw,     // swizzled B fragments
    const float* __restrict__ wm,       // [MPAD]
    const int* __restrict__ row_seg,    // [N_ENV]
    float* __restrict__ out) {          // [NSTR]
  extern __shared__ unsigned short As[];   // [128][LDST] = 108544 B

  const int tid  = threadIdx.x;
  const int lane = tid & 63;
  const int wid  = tid >> 6;            // 0..7
  const int wrow = wid >> 2;            // 0..1  (row half)
  const int wcol = wid & 3;             // 0..3  (64-col group within 256)
  const long row_base = (long)blockIdx.x * BM;

  // ---- Pass 1: coalesced fp32 -> bf16 -> LDS (unnormalized) --------------
  {
    const float4* Ag = (const float4*)(A + row_base * DIM);
    int rows_valid = (int)(N_ENV - row_base);          // may exceed 128
    if (rows_valid > BM) rows_valid = BM;
#pragma unroll 5
    for (int c = tid; c < BM * (DIM / 4); c += 512) {  // 12800 float4 chunks
      int row = c / 100;                               // 100 float4 per row
      int kc  = c - row * 100;
      uint2 packed = (uint2){0u, 0u};
      if (row < rows_valid) {
        float4 v = Ag[c];
        packed.x = (unsigned int)f2bf(v.x) | ((unsigned int)f2bf(v.y) << 16);
        packed.y = (unsigned int)f2bf(v.z) | ((unsigned int)f2bf(v.w) << 16);
      }
      *(uint2*)&As[row * LDST + kc * 4] = packed;
    }
    // Zero the K-pad tail [400, 424) for every row: the K-loop reads
    // fragments up to column 416 (kt=12, koff 16/24). 24 shorts = 3 x 16B.
    if (tid < BM) {
      uint4 z = (uint4){0u, 0u, 0u, 0u};
      uint4* zp = (uint4*)&As[tid * LDST + 400];
      zp[0] = z; zp[1] = z; zp[2] = z;
    }
  }
  __syncthreads();

  // ---- Pass 2+3: per-row norm from LDS, scale in place -------------------
  // 512 threads / 128 rows -> 4 threads per row, 104 shorts each (the q=3
  // quarter covers [312,416): includes the zeroed pad, harmless).
  {
    int row = tid >> 2, q = tid & 3;
    unsigned short* rp = &As[row * LDST + q * 104];
    short8 vals[13];
    float ss = 0.f;
#pragma unroll
    for (int i = 0; i < 13; ++i) {
      vals[i] = *(const short8*)(rp + i * 8);
#pragma unroll
      for (int e = 0; e < 8; ++e) {
        float f = bf2f((unsigned short)vals[i][e]);
        ss += f * f;
      }
    }
    ss += __shfl_xor(ss, 1);
    ss += __shfl_xor(ss, 2);
    float rn = (ss > 0.f) ? rsqrtf(ss) : 0.f;
#pragma unroll
    for (int i = 0; i < 13; ++i) {
      short8 o;
#pragma unroll
      for (int e = 0; e < 8; ++e)
        o[e] = (short)f2bf(bf2f((unsigned short)vals[i][e]) * rn);
      *(short8*)(rp + i * 8) = o;
    }
  }
  __syncthreads();

  // ---- Main loop ---------------------------------------------------------
  const int frow = lane & 15;
  const int koff = (lane >> 4) * 8;
  const unsigned short* Abase = &As[(wrow * 64 + frow) * LDST + koff];

  float vacc[4][4];
#pragma unroll
  for (int i = 0; i < 4; ++i)
#pragma unroll
    for (int r = 0; r < 4; ++r) vacc[i][r] = 0.f;

#pragma unroll 1
  for (int mt = 0; mt < MSTEPS; ++mt) {
    const int panel = mt * 2 + (wcol >> 1);   // 128-col panel in Bsw layout
    const int cfb   = (wcol & 1) * 4;         // col-frag base within panel

    float4v acc[4][4];
#pragma unroll
    for (int i = 0; i < 4; ++i)
#pragma unroll
      for (int j = 0; j < 4; ++j) acc[i][j] = (float4v){0.f, 0.f, 0.f, 0.f};

    short8 afc[4], bfc[4], afn[4], bfn[4];
    const short8* Bp0 = Bsw + (((size_t)panel * KTILES) * 8 + cfb) * 64 + lane;
#pragma unroll
    for (int i = 0; i < 4; ++i)
      afc[i] = *(const short8*)(Abase + i * (16 * LDST));
#pragma unroll
    for (int j = 0; j < 4; ++j) bfc[j] = Bp0[j * 64];

#pragma unroll 1
    for (int kt = 0; kt < KTILES; ++kt) {
      if (kt < KTILES - 1) {
        const unsigned short* An = Abase + (kt + 1) * 32;
#pragma unroll
        for (int i = 0; i < 4; ++i)
          afn[i] = *(const short8*)(An + i * (16 * LDST));
        const short8* Bn =
            Bsw + (((size_t)panel * KTILES + kt + 1) * 8 + cfb) * 64 + lane;
#pragma unroll
        for (int j = 0; j < 4; ++j) bfn[j] = Bn[j * 64];
      }
#pragma unroll
      for (int i = 0; i < 4; ++i)
#pragma unroll
        for (int j = 0; j < 4; ++j)
          acc[i][j] = __builtin_amdgcn_mfma_f32_16x16x32_bf16(
              afc[i], bfc[j], acc[i][j], 0, 0, 0);
      if (kt < KTILES - 1) {
#pragma unroll
        for (int i = 0; i < 4; ++i) afc[i] = afn[i];
#pragma unroll
        for (int j = 0; j < 4; ++j) bfc[j] = bfn[j];
      }
    }

    // epilogue: vacc[row] += wm[col] * C^2 over this wave's 4 col-frags
    float wmv[4];
#pragma unroll
    for (int j = 0; j < 4; ++j)
      wmv[j] = wm[panel * 128 + cfb * 16 + j * 16 + frow];
#pragma unroll
    for (int i = 0; i < 4; ++i)
#pragma unroll
      for (int r = 0; r < 4; ++r) {
        float s = 0.f;
#pragma unroll
        for (int j = 0; j < 4; ++j) {
          float c = acc[i][j][r];
          s += wmv[j] * c * c;
        }
        vacc[i][r] += s;
      }
  }

  // cross-lane reduce over 16-lane groups (same C/D rows), then atomics
#pragma unroll
  for (int i = 0; i < 4; ++i)
#pragma unroll
    for (int r = 0; r < 4; ++r) {
      float s = vacc[i][r];
      s += __shfl_xor(s, 1);
      s += __shfl_xor(s, 2);
      s += __shfl_xor(s, 4);
      s += __shfl_xor(s, 8);
      if ((lane & 15) == 0) {
        long n = row_base + wrow * 64 + i * 16 + (lane >> 4) * 4 + r;
        if (n < N_ENV) atomicAdd(&out[row_seg[n]], s);
      }
    }
}

// ---------------------------------------------------------------------------
extern "C" void kernel_launch(void* const* d_in, const int* in_sizes, int n_in,
                              void* d_out, int out_size, void* d_ws, size_t ws_size,
                              hipStream_t stream) {
  const float* ps      = (const float*)d_in[0];  // [N_ENV, DIM]
  const float* sp      = (const float*)d_in[1];  // [MPTS, DIM]
  const float* w       = (const float*)d_in[2];  // [1, NTRN]
  // d_in[3] = all_species: unused by the reference
  const int*   row_seg = (const int*)d_in[4];    // [N_ENV]
  const int*   col_seg = (const int*)d_in[5];    // [MPTS]
  float* out = (float*)d_out;                    // [NSTR]

  char* ws = (char*)d_ws;
  const size_t B_BYTES = (size_t)16 * KTILES * 8 * 64 * 16;  // 1,703,936
  short8* Bsw = (short8*)ws;
  float*  wm  = (float*)(ws + B_BYTES);

  const int LDS_BYTES = BM * LDST * 2;   // 108544
  (void)hipFuncSetAttribute((const void*)gemm_fused_kernel,
                            hipFuncAttributeMaxDynamicSharedMemorySize,
                            LDS_BYTES);

  prep_kernel<<<MPAD / 256, 256, 0, stream>>>(w, col_seg, wm, out);
  bswz_kernel<<<(16 * KTILES * 8 * 64) / 256, 256, 0, stream>>>(sp, Bsw);
  gemm_fused_kernel<<<NPAD / BM, 512, LDS_BYTES, stream>>>(ps, Bsw, wm, row_seg, out);
}